// Round 6
// baseline (842.682 us; speedup 1.0000x reference)
//
#include <hip/hip_runtime.h>
#include <hip/hip_cooperative_groups.h>
namespace cg = cooperative_groups;

#define TT 32
#define BETA_ 0.8f

typedef __bf16 bf16_t;
typedef bf16_t bf16x8 __attribute__((ext_vector_type(8)));
typedef float f32x4 __attribute__((ext_vector_type(4)));

// ---------------- workspace layout ----------------
#define PACC_F 256
#define BF_BASE_B 263168L             // byte offset of bf16 region (16B aligned)
// bf16 region = array of 4-plane units (planes: 0 rH, 1 iH, 2 rL, 3 iL), 262144 elems.
// Units: 0 Ux, 1 Uh, 2 UhT, 3 Psi, 4..11 {P1,PT1,P2,PT2,P3,PT3,P4,PT4},
//        12..43 Phi[a], 44..75 H[c].  Then Xi: 32 x 2-plane units (131072) at XIB_E.
#define US4 262144L
#define XU  131072L
#define XIB_E (76L * US4)

__device__ inline f32x4 MF(bf16x8 a, bf16x8 b, f32x4 c) {
    return __builtin_amdgcn_mfma_f32_16x16x32_bf16(a, b, c, 0, 0, 0);
}

__device__ inline void splitW(float vr, float vi, bf16_t* o, long idx, int full) {
    bf16_t rh = (bf16_t)vr; o[idx] = rh;
    bf16_t ih = (bf16_t)vi; o[65536L + idx] = ih;
    if (full) {
        o[2 * 65536L + idx] = (bf16_t)(vr - (float)rh);
        o[3 * 65536L + idx] = (bf16_t)(vi - (float)ih);
    }
}

struct P {
    const float *xt, *xa, *xv, *sm, *Wt, *bt, *Wa, *ba, *Wv, *bv, *Pt, *Pa, *Pv;
    const float *Uxr, *Uxi, *Uhr, *Uhi, *Lam, *Kr, *Ki, *W1, *b1, *W2, *b2;
    float* out;
    long aB[7][4], aS[7][4], bB[7][4], cB[7][4], cS[7][4];
    int cnt[7][4];
    int njobs[7];
    int mpref[33];
    int mtot;
};

// ---------------- prep jobs: coef / split U / psi / norm / zero PACC ----------------
__device__ void prep_job(int job, int tid, const P& p, float* WF, bf16_t* bf, char* smem)
{
    float* red  = (float*)smem;            // 256
    float* rt   = red + 256;               // 4
    float* ra   = rt + 4;                  // 8
    float* rv   = ra + 8;                  // 8
    float* inv3 = rv + 8;                  // 3

    if (job == 0) {
        if (tid != 0) return;
        float lam = 1.f / (1.f + expf(-p.Lam[0]));
        float oml = 1.f - lam;
        WF[0] = lam;
        WF[1] = BETA_ * BETA_ * lam * lam;
        float w = 1.f;
        for (int n = 0; n < 64; ++n) { WF[64 + n] = w; w *= oml; }
        float a1 = 1.f / 256.f, a2 = 1.f / 256.f;
        for (int t = 0; t < 32; ++t) {
            a1 = oml * a1;
            float y1 = BETA_ * a1 + (1.f - BETA_) / 256.f;
            a2 = lam * y1 + oml * a2;
            WF[8 + t] = BETA_ * a2 + (1.f - BETA_) / 256.f;
        }
        return;
    }
    if (job < 513) {                       // split Ux (1..256) / Uh+UhT (257..512)
        int i = (job - 1) & 255, jj = tid;
        if (job < 257) {
            splitW(p.Uxr[i * 256 + jj], p.Uxi[i * 256 + jj], bf + 0 * US4, (long)i * 256 + jj, 1);
        } else {
            float vr = p.Uhr[i * 256 + jj], vi = p.Uhi[i * 256 + jj];
            splitW(vr, vi, bf + 1 * US4, (long)i * 256 + jj, 1);
            splitW(vr, vi, bf + 2 * US4, (long)jj * 256 + i, 1);
        }
        return;
    }
    if (job < 769) {                       // psi, colS = t0*8+b
        const int colS = job - 513;
        const int t0 = colS >> 3, b = colS & 7;
        const long bt_ = (long)b * TT + t0;
        if (tid < 4) {
            float acc = p.bt[tid];
            const float* x = p.xt + bt_ * 300;
            for (int q = 0; q < 300; ++q) acc = fmaf(x[q], p.Wt[q * 4 + tid], acc);
            rt[tid] = fmaxf(acc, 0.f);
        } else if (tid < 12) {
            int u = tid - 4;
            float acc = p.ba[u];
            const float* x = p.xa + bt_ * 74;
            for (int q = 0; q < 74; ++q) acc = fmaf(x[q], p.Wa[q * 8 + u], acc);
            ra[u] = fmaxf(acc, 0.f);
        } else if (tid < 20) {
            int u = tid - 12;
            float acc = p.bv[u];
            const float* x = p.xv + bt_ * 35;
            for (int q = 0; q < 35; ++q) acc = fmaf(x[q], p.Wv[q * 8 + u], acc);
            rv[u] = fmaxf(acc, 0.f);
        }
        __syncthreads();
        if (tid == 0) {
            float s = 0.f; for (int u = 0; u < 4; ++u) s += rt[u] * rt[u];
            inv3[0] = 1.f / fmaxf(sqrtf(s), 1e-12f);
            s = 0.f; for (int u = 0; u < 8; ++u) s += ra[u] * ra[u];
            inv3[1] = 1.f / fmaxf(sqrtf(s), 1e-12f);
            s = 0.f; for (int u = 0; u < 8; ++u) s += rv[u] * rv[u];
            inv3[2] = 1.f / fmaxf(sqrtf(s), 1e-12f);
        }
        __syncthreads();
        float s0 = p.sm[bt_ * 2], s1 = p.sm[bt_ * 2 + 1];
        int spk = (s1 > s0) ? 1 : 0;
        int d = tid;
        int ti = d >> 6, ai = (d >> 3) & 7, vi = d & 7;
        float amp = (rt[ti] * inv3[0]) * (ra[ai] * inv3[1]) * (rv[vi] * inv3[2]);
        float ph = p.Pt[spk * 4 + ti] + p.Pa[spk * 8 + ai] + p.Pv[spk * 8 + vi];
        splitW(amp * cosf(ph), amp * sinf(ph), bf + 3 * US4, (long)colS * 256 + d, 1);
        __syncthreads();
        return;
    }
    if (job < 1025) {                      // norm: H0 = conj(normalized K rows) -> unit 44
        int k = job - 769, i = tid;
        float vr = p.Kr[k * 256 + i], vi = p.Ki[k * 256 + i];
        red[i] = vr * vr + vi * vi;
        __syncthreads();
        for (int s = 128; s > 0; s >>= 1) { if (i < s) red[i] += red[i + s]; __syncthreads(); }
        float inv = 1.f / sqrtf(red[0]);
        splitW(vr * inv, -vi * inv, bf + 44 * US4, (long)k * 256 + i, 1);
        __syncthreads();
        return;
    }
    // zero PACC: jobs 1025..1280
    WF[PACC_F + (job - 1025) * 256 + tid] = 0.f;
}

// ---------------- chain GEMM job ----------------
template<int LO>
__device__ void gemm_job(int s, int job, int tid, const P& p, bf16_t* bf, char* smem)
{
    constexpr int NP = LO ? 2 : 4;
    int z = job >> 4;
    const int m0 = (job & 3) * 64, n0 = ((job >> 2) & 3) * 64;
    int j = 0;
    while (z >= p.cnt[s][j]) { z -= p.cnt[s][j]; ++j; }
    const bf16_t* A = bf + p.aB[s][j] + (long)z * p.aS[s][j];
    const bf16_t* B = bf + p.bB[s][j];
    bf16_t*       C = bf + p.cB[s][j] + (long)z * p.cS[s][j];

    bf16_t (*sA)[64][40] = (bf16_t(*)[64][40])smem;
    bf16_t (*sB)[64][40] = (bf16_t(*)[64][40])(smem + NP * 64 * 40 * 2);
    const int lane = tid & 63, w = tid >> 6;
    const int wm = w >> 1, wn = w & 1;
    const int fr = lane & 15, fg = lane >> 4;
    const int r_ = tid >> 2, cch = tid & 3;

    f32x4 rp[2][2] = {}, rn[2][2] = {}, im[2][2] = {};
    uint4 pa[NP], pb[NP];

#pragma unroll
    for (int pl = 0; pl < NP; ++pl) {
        pa[pl] = *(const uint4*)(A + (long)pl * 65536 + (long)(m0 + r_) * 256 + cch * 8);
        pb[pl] = *(const uint4*)(B + (long)pl * 65536 + (long)(n0 + r_) * 256 + cch * 8);
    }
    for (int ks = 0; ks < 8; ++ks) {
        __syncthreads();
#pragma unroll
        for (int pl = 0; pl < NP; ++pl) {
            *(uint4*)(&sA[pl][r_][cch * 8]) = pa[pl];
            *(uint4*)(&sB[pl][r_][cch * 8]) = pb[pl];
        }
        __syncthreads();
        if (ks < 7) {
#pragma unroll
            for (int pl = 0; pl < NP; ++pl) {
                pa[pl] = *(const uint4*)(A + (long)pl * 65536 + (long)(m0 + r_) * 256 + (ks + 1) * 32 + cch * 8);
                pb[pl] = *(const uint4*)(B + (long)pl * 65536 + (long)(n0 + r_) * 256 + (ks + 1) * 32 + cch * 8);
            }
        }
        bf16x8 aF[2][NP], bF[2][NP];
#pragma unroll
        for (int fm = 0; fm < 2; ++fm) {
            int row = wm * 32 + fm * 16 + fr;
#pragma unroll
            for (int pl = 0; pl < NP; ++pl) aF[fm][pl] = *(const bf16x8*)(&sA[pl][row][fg * 8]);
        }
#pragma unroll
        for (int fn = 0; fn < 2; ++fn) {
            int row = wn * 32 + fn * 16 + fr;
#pragma unroll
            for (int pl = 0; pl < NP; ++pl) bF[fn][pl] = *(const bf16x8*)(&sB[pl][row][fg * 8]);
        }
#pragma unroll
        for (int fm = 0; fm < 2; ++fm)
#pragma unroll
            for (int fn = 0; fn < 2; ++fn) {
                f32x4 p_ = rp[fm][fn], n_ = rn[fm][fn], i_ = im[fm][fn];
                p_ = MF(aF[fm][0], bF[fn][0], p_);
                n_ = MF(aF[fm][1], bF[fn][1], n_);
                i_ = MF(aF[fm][0], bF[fn][1], i_);
                i_ = MF(aF[fm][1], bF[fn][0], i_);
                if (!LO) {
                    p_ = MF(aF[fm][0], bF[fn][2], p_);
                    p_ = MF(aF[fm][2], bF[fn][0], p_);
                    n_ = MF(aF[fm][1], bF[fn][3], n_);
                    n_ = MF(aF[fm][3], bF[fn][1], n_);
                    i_ = MF(aF[fm][0], bF[fn][3], i_);
                    i_ = MF(aF[fm][2], bF[fn][1], i_);
                    i_ = MF(aF[fm][1], bF[fn][2], i_);
                    i_ = MF(aF[fm][3], bF[fn][0], i_);
                }
                rp[fm][fn] = p_; rn[fm][fn] = n_; im[fm][fn] = i_;
            }
    }
#pragma unroll
    for (int fm = 0; fm < 2; ++fm)
#pragma unroll
        for (int fn = 0; fn < 2; ++fn)
#pragma unroll
            for (int r4 = 0; r4 < 4; ++r4) {
                int m = m0 + wm * 32 + fm * 16 + fg * 4 + r4;
                int n = n0 + wn * 32 + fn * 16 + fr;
                float vr = rp[fm][fn][r4] - rn[fm][fn][r4];
                splitW(vr, im[fm][fn][r4], C, (long)m * 256 + n, !LO);
            }
}

// ---------------- measurement job (flat list, cross-c pipelined) ----------------
__device__ void measure_job(int job, int tid, const P& p, float* WF, bf16_t* bf, char* smem)
{
    int t = 0;
    while (job >= p.mpref[t + 1]) ++t;
    int jid = job - p.mpref[t];
    const int kblk = jid & 3;
    int g = jid >> 2;
    int i = 0;
    for (;;) { int cnt2 = ((t - 4 * i) >> 3) + 1; if (g < cnt2) break; g -= cnt2; ++i; }
    const int clo = 4 * i, colc = g;
    const int chi = (clo + 4 < t + 1) ? clo + 4 : t + 1;
    const int k0 = kblk * 64;
    const int S = (chi - clo) * 8;

    bf16_t (*sA)[40] = (bf16_t(*)[40])smem;                    // [2*64][40] A planes
    bf16_t (*sB)[40] = (bf16_t(*)[40])(smem + 10240);          // [2*64][40] B planes
    float (*part)[9] = (float(*)[9])(smem + 20480);            // [64][9]
    const int lane = tid & 63, w = tid >> 6;
    const int wm = w >> 1, wn = w & 1;
    const int fr = lane & 15, fg = lane >> 4;
    const int r_ = tid >> 2, cch = tid & 3;
    float sacc[2][2][4] = {};

    const int t0r = colc * 8 + (r_ >> 3);
    const long xrow = (long)(t0r * 8 + (r_ & 7)) * 256;

    f32x4 rp[2][2] = {}, rn[2][2] = {}, im[2][2] = {};
    uint4 pa[2], pb[2];
    {   // prologue: load step 0
        const bf16_t* H = bf + (44L + clo) * US4;
        const int av = t - clo - t0r;
#pragma unroll
        for (int pl = 0; pl < 2; ++pl) {
            pa[pl] = *(const uint4*)(H + (long)pl * 65536 + (long)(k0 + r_) * 256 + cch * 8);
            uint4 v = {0u, 0u, 0u, 0u};
            if (av >= 0)
                v = *(const uint4*)(bf + XIB_E + (long)av * XU + (long)pl * 65536 + xrow + cch * 8);
            pb[pl] = v;
        }
    }
    for (int s = 0; s < S; ++s) {
        __syncthreads();
#pragma unroll
        for (int pl = 0; pl < 2; ++pl) {
            *(uint4*)(&sA[pl * 64 + r_][cch * 8]) = pa[pl];
            *(uint4*)(&sB[pl * 64 + r_][cch * 8]) = pb[pl];
        }
        __syncthreads();
        if (s + 1 < S) {
            const int s2 = s + 1;
            const int c2 = clo + (s2 >> 3), ks2 = s2 & 7;
            const bf16_t* H = bf + (44L + c2) * US4;
            const int av = t - c2 - t0r;
#pragma unroll
            for (int pl = 0; pl < 2; ++pl) {
                pa[pl] = *(const uint4*)(H + (long)pl * 65536 + (long)(k0 + r_) * 256 + ks2 * 32 + cch * 8);
                uint4 v = {0u, 0u, 0u, 0u};
                if (av >= 0)
                    v = *(const uint4*)(bf + XIB_E + (long)av * XU + (long)pl * 65536 + xrow + ks2 * 32 + cch * 8);
                pb[pl] = v;
            }
        }
        bf16x8 aF[2][2], bF[2][2];
#pragma unroll
        for (int fm = 0; fm < 2; ++fm) {
            int row = wm * 32 + fm * 16 + fr;
#pragma unroll
            for (int pl = 0; pl < 2; ++pl) aF[fm][pl] = *(const bf16x8*)(&sA[pl * 64 + row][fg * 8]);
        }
#pragma unroll
        for (int fn = 0; fn < 2; ++fn) {
            int row = wn * 32 + fn * 16 + fr;
#pragma unroll
            for (int pl = 0; pl < 2; ++pl) bF[fn][pl] = *(const bf16x8*)(&sB[pl * 64 + row][fg * 8]);
        }
#pragma unroll
        for (int fm = 0; fm < 2; ++fm)
#pragma unroll
            for (int fn = 0; fn < 2; ++fn) {
                f32x4 p_ = rp[fm][fn], n_ = rn[fm][fn], i_ = im[fm][fn];
                p_ = MF(aF[fm][0], bF[fn][0], p_);
                n_ = MF(aF[fm][1], bF[fn][1], n_);
                i_ = MF(aF[fm][0], bF[fn][1], i_);
                i_ = MF(aF[fm][1], bF[fn][0], i_);
                rp[fm][fn] = p_; rn[fm][fn] = n_; im[fm][fn] = i_;
            }
        if ((s & 7) == 7) {
#pragma unroll
            for (int fm = 0; fm < 2; ++fm)
#pragma unroll
                for (int fn = 0; fn < 2; ++fn) {
#pragma unroll
                    for (int r4 = 0; r4 < 4; ++r4) {
                        float vr = rp[fm][fn][r4] - rn[fm][fn][r4];
                        float vi = im[fm][fn][r4];
                        sacc[fm][fn][r4] += vr * vr + vi * vi;
                    }
                    rp[fm][fn] = (f32x4){0.f, 0.f, 0.f, 0.f};
                    rn[fm][fn] = (f32x4){0.f, 0.f, 0.f, 0.f};
                    im[fm][fn] = (f32x4){0.f, 0.f, 0.f, 0.f};
                }
        }
    }
    for (int e = tid; e < 64 * 9; e += 256) (&part[0][0])[e] = 0.f;
    __syncthreads();
#pragma unroll
    for (int fm = 0; fm < 2; ++fm)
#pragma unroll
        for (int fn = 0; fn < 2; ++fn)
#pragma unroll
            for (int r4 = 0; r4 < 4; ++r4) {
                int kl = wm * 32 + fm * 16 + fg * 4 + r4;
                int g2 = wn * 32 + fn * 16 + fr;
                int t0 = colc * 8 + (g2 >> 3);
                if (t0 <= t) atomicAdd(&part[kl][g2 & 7], WF[64 + t - t0] * sacc[fm][fn][r4]);
            }
    __syncthreads();
    float* pacc = WF + PACC_F;
    for (int e = tid; e < 512; e += 256) {
        int kl = e >> 3, b = e & 7;
        float v = part[kl][b];
        if (v != 0.f) atomicAdd(&pacc[((t * 8 + b) << 8) + k0 + kl], v);
    }
    __syncthreads();
}

// ---------------- MLP job ----------------
__device__ void mlp_job(int job, int tid, const P& p, float* WF, char* smem)
{
    const int t = job >> 3, b = job & 7;
    float* pp = (float*)smem;       // 256
    float* hh = pp + 256;           // 64
    float* oo = hh + 64;            // 6
    float ft = WF[8 + t], s2 = WF[1];
    const float* pacc = WF + PACC_F + (((t * 8 + b)) << 8);
    pp[tid] = ft + s2 * pacc[tid];
    __syncthreads();
    if (tid < 64) {
        float acc = p.b1[tid];
        for (int k = 0; k < 256; ++k) acc = fmaf(pp[k], p.W1[k * 64 + tid], acc);
        hh[tid] = fmaxf(acc, 0.f);
    }
    __syncthreads();
    if (tid < 6) {
        float a = p.b2[tid];
        for (int k = 0; k < 64; ++k) a = fmaf(hh[k], p.W2[k * 6 + tid], a);
        oo[tid] = tanhf(a);
    }
    __syncthreads();
    if (tid == 0) {
        float m = oo[0];
        for (int c2 = 1; c2 < 6; ++c2) m = fmaxf(m, oo[c2]);
        float s = 0.f;
        for (int c2 = 0; c2 < 6; ++c2) s += expf(oo[c2] - m);
        float lse = m + logf(s);
        for (int c2 = 0; c2 < 6; ++c2) p.out[((long)b * 32 + t) * 6 + c2] = oo[c2] - lse;
    }
    __syncthreads();
}

// ---------------- the persistent cooperative kernel ----------------
__global__ __launch_bounds__(256, 3) void k_all(void* wsv, P p)
{
    float* WF = (float*)wsv;
    bf16_t* bf = (bf16_t*)((char*)wsv + BF_BASE_B);
    __shared__ __align__(16) char smem[40960];
    cg::grid_group grid = cg::this_grid();
    const int tid = threadIdx.x;
    const int nb = gridDim.x;

    for (int job = blockIdx.x; job < 1281; job += nb)
        prep_job(job, tid, p, WF, bf, smem);
    grid.sync();

    for (int s = 0; s < 6; ++s) {
        for (int job = blockIdx.x; job < p.njobs[s]; job += nb)
            gemm_job<0>(s, job, tid, p, bf, smem);
        grid.sync();
    }
    for (int job = blockIdx.x; job < p.njobs[6]; job += nb)
        gemm_job<1>(6, job, tid, p, bf, smem);
    grid.sync();

    for (int job = blockIdx.x; job < p.mtot; job += nb)
        measure_job(job, tid, p, WF, bf, smem);
    grid.sync();

    for (int job = blockIdx.x; job < 256; job += nb)
        mlp_job(job, tid, p, WF, smem);
}

// ---------------- host ----------------
static inline void setJob(P& p, int s, int i, long aB, long aS, long bB, long cB, long cS, int cnt)
{
    p.aB[s][i] = aB; p.aS[s][i] = aS; p.bB[s][i] = bB; p.cB[s][i] = cB; p.cS[s][i] = cS;
    p.cnt[s][i] = cnt;
}

extern "C" void kernel_launch(void* const* d_in, const int* in_sizes, int n_in,
                              void* d_out, int out_size, void* d_ws, size_t ws_size,
                              hipStream_t stream)
{
    P p;
    p.xt  = (const float*)d_in[0];
    p.xa  = (const float*)d_in[1];
    p.xv  = (const float*)d_in[2];
    p.sm  = (const float*)d_in[3];
    p.Wt  = (const float*)d_in[4];
    p.bt  = (const float*)d_in[5];
    p.Wa  = (const float*)d_in[6];
    p.ba  = (const float*)d_in[7];
    p.Wv  = (const float*)d_in[8];
    p.bv  = (const float*)d_in[9];
    p.Pt  = (const float*)d_in[10];
    p.Pa  = (const float*)d_in[11];
    p.Pv  = (const float*)d_in[12];
    p.Uxr = (const float*)d_in[13];
    p.Uxi = (const float*)d_in[14];
    p.Uhr = (const float*)d_in[15];
    p.Uhi = (const float*)d_in[16];
    p.Lam = (const float*)d_in[17];
    p.Kr  = (const float*)d_in[18];
    p.Ki  = (const float*)d_in[19];
    p.W1  = (const float*)d_in[20];
    p.b1  = (const float*)d_in[21];
    p.W2  = (const float*)d_in[22];
    p.b2  = (const float*)d_in[23];
    p.out = (float*)d_out;

    auto U = [](int u) { return (long)u * US4; };

    // S1: P1, PT1, Phi0 = Ux*Psi, H1 = H0*UhT
    setJob(p, 0, 0, U(1), 0, U(2), U(4), 0, 1);
    setJob(p, 0, 1, U(2), 0, U(1), U(5), 0, 1);
    setJob(p, 0, 2, U(3), 0, U(0), U(12), 0, 1);
    setJob(p, 0, 3, U(44), 0, U(2), U(45), 0, 1);
    p.njobs[0] = 16 * 4;
    // S2: P2, PT2, Phi1 (B=Uh), H{2,3} (B=PT1)
    setJob(p, 1, 0, U(4), 0, U(5), U(6), 0, 1);
    setJob(p, 1, 1, U(5), 0, U(4), U(7), 0, 1);
    setJob(p, 1, 2, U(12), 0, U(1), U(13), 0, 1);
    setJob(p, 1, 3, U(44), US4, U(5), U(46), US4, 2);
    p.njobs[1] = 16 * 5;
    // S3: P3, PT3, Phi{2,3} (B=P1), H{4..7} (B=PT2)
    setJob(p, 2, 0, U(6), 0, U(7), U(8), 0, 1);
    setJob(p, 2, 1, U(7), 0, U(6), U(9), 0, 1);
    setJob(p, 2, 2, U(12), US4, U(4), U(14), US4, 2);
    setJob(p, 2, 3, U(44), US4, U(7), U(48), US4, 4);
    p.njobs[2] = 16 * 8;
    // S4: P4, PT4, Phi{4..7} (B=P2), H{8..15} (B=PT3)
    setJob(p, 3, 0, U(8), 0, U(9), U(10), 0, 1);
    setJob(p, 3, 1, U(9), 0, U(8), U(11), 0, 1);
    setJob(p, 3, 2, U(12), US4, U(6), U(16), US4, 4);
    setJob(p, 3, 3, U(44), US4, U(9), U(52), US4, 8);
    p.njobs[3] = 16 * 14;
    // S5: Phi{8..15} (B=P3), H{16..31} (B=PT4)
    setJob(p, 4, 0, U(12), US4, U(8), U(20), US4, 8);
    setJob(p, 4, 1, U(44), US4, U(11), U(60), US4, 16);
    setJob(p, 4, 2, 0, 0, 0, 0, 0, 0);
    setJob(p, 4, 3, 0, 0, 0, 0, 0, 0);
    p.njobs[4] = 16 * 24;
    // S6: Phi{16..31} (B=P4)
    setJob(p, 5, 0, U(12), US4, U(10), U(28), US4, 16);
    setJob(p, 5, 1, 0, 0, 0, 0, 0, 0);
    setJob(p, 5, 2, 0, 0, 0, 0, 0, 0);
    setJob(p, 5, 3, 0, 0, 0, 0, 0, 0);
    p.njobs[5] = 16 * 16;
    // S7: Xi{0..31} = Ux*Phi (hi-only in/out)
    setJob(p, 6, 0, U(12), US4, U(0), XIB_E, XU, 32);
    setJob(p, 6, 1, 0, 0, 0, 0, 0, 0);
    setJob(p, 6, 2, 0, 0, 0, 0, 0, 0);
    setJob(p, 6, 3, 0, 0, 0, 0, 0, 0);
    p.njobs[6] = 16 * 32;

    p.mpref[0] = 0;
    for (int t = 0; t < 32; ++t) {
        int G = 0;
        for (int i2 = 0; 4 * i2 <= t; ++i2) G += ((t - 4 * i2) >> 3) + 1;
        p.mpref[t + 1] = p.mpref[t] + G * 4;
    }
    p.mtot = p.mpref[32];

    int maxb = 0;
    if (hipOccupancyMaxActiveBlocksPerMultiprocessor(&maxb, (const void*)k_all, 256, 0)
            != hipSuccess || maxb < 1)
        maxb = 2;
    int grid = maxb * 256;
    if (grid > 768) grid = 768;

    void* wsp = d_ws;
    void* args[2] = { (void*)&wsp, (void*)&p };
    hipLaunchCooperativeKernel((const void*)k_all, dim3(grid), dim3(256), args, 0, stream);
}

// Round 7
// 424.265 us; speedup vs baseline: 1.9862x; 1.9862x over previous
//
#include <hip/hip_runtime.h>

#define TT 32
#define BETA_ 0.8f

typedef __bf16 bf16_t;
typedef bf16_t bf16x8 __attribute__((ext_vector_type(8)));
typedef float f32x4 __attribute__((ext_vector_type(4)));

// ---------------- workspace layout ----------------
// f32 region: [0..256) coefs, [256..65792) PACC
#define PACC_F 256
#define BF_BASE_B 263168L             // byte offset of bf16 region (16B aligned)
// bf16 region = array of 4-plane units (planes: 0 rH, 1 iH, 2 rL, 3 iL), 262144 elems.
// Units: 0 Ux, 1 Uh, 2 UhT, 3 Psi, 4..11 {P1,PT1,P2,PT2,P3,PT3,P4,PT4},
//        12..43 Phi[a], 44..75 H[c].  Then Xi: 32 x 2-plane units (131072) at XIB_E.
#define US4 262144L
#define XU  131072L
#define XIB_E (76L * US4)

__device__ inline f32x4 MF(bf16x8 a, bf16x8 b, f32x4 c) {
    return __builtin_amdgcn_mfma_f32_16x16x32_bf16(a, b, c, 0, 0, 0);
}

__device__ inline void splitW(float vr, float vi, bf16_t* o, long idx, int full) {
    bf16_t rh = (bf16_t)vr; o[idx] = rh;
    bf16_t ih = (bf16_t)vi; o[65536L + idx] = ih;
    if (full) {
        o[2 * 65536L + idx] = (bf16_t)(vr - (float)rh);
        o[3 * 65536L + idx] = (bf16_t)(vi - (float)ih);
    }
}

// ---------------- fused prep: coef + split U + psi + norm ----------------
__global__ __launch_bounds__(256) void k_prep(
    const float* __restrict__ xt, const float* __restrict__ xa, const float* __restrict__ xv,
    const float* __restrict__ sm,
    const float* __restrict__ Wt, const float* __restrict__ bt,
    const float* __restrict__ Wa, const float* __restrict__ ba,
    const float* __restrict__ Wv, const float* __restrict__ bv,
    const float* __restrict__ Pt, const float* __restrict__ Pa, const float* __restrict__ Pv,
    const float* __restrict__ Uxr, const float* __restrict__ Uxi,
    const float* __restrict__ Uhr, const float* __restrict__ Uhi,
    const float* __restrict__ Lam, const float* __restrict__ Kr, const float* __restrict__ Ki,
    void* wsv)
{
    float* WF = (float*)wsv;
    bf16_t* bf = (bf16_t*)((char*)wsv + BF_BASE_B);
    const int blk = blockIdx.x, tid = threadIdx.x;
    __shared__ float red[256];
    __shared__ float rt[4], ra[8], rv[8], inv3[3];

    if (blk == 0) {
        if (tid != 0) return;
        float lam = 1.f / (1.f + expf(-Lam[0]));
        float oml = 1.f - lam;
        WF[0] = lam;
        WF[1] = BETA_ * BETA_ * lam * lam;
        float w = 1.f;
        for (int n = 0; n < 64; ++n) { WF[64 + n] = w; w *= oml; }
        float a1 = 1.f / 256.f, a2 = 1.f / 256.f;
        for (int t = 0; t < 32; ++t) {
            a1 = oml * a1;
            float y1 = BETA_ * a1 + (1.f - BETA_) / 256.f;
            a2 = lam * y1 + oml * a2;
            WF[8 + t] = BETA_ * a2 + (1.f - BETA_) / 256.f;
        }
        return;
    }
    if (blk < 513) {                       // split Ux (1..256) / Uh+UhT (257..512)
        int i = (blk - 1) & 255, j = tid;
        if (blk < 257) {
            splitW(Uxr[i * 256 + j], Uxi[i * 256 + j], bf + 0 * US4, (long)i * 256 + j, 1);
        } else {
            float vr = Uhr[i * 256 + j], vi = Uhi[i * 256 + j];
            splitW(vr, vi, bf + 1 * US4, (long)i * 256 + j, 1);
            splitW(vr, vi, bf + 2 * US4, (long)j * 256 + i, 1);
        }
        return;
    }
    if (blk < 769) {                       // psi, colS = t0*8+b
        const int colS = blk - 513;
        const int t0 = colS >> 3, b = colS & 7;
        const long bt_ = (long)b * TT + t0;
        if (tid < 4) {
            float acc = bt[tid];
            const float* x = xt + bt_ * 300;
            for (int q = 0; q < 300; ++q) acc = fmaf(x[q], Wt[q * 4 + tid], acc);
            rt[tid] = fmaxf(acc, 0.f);
        } else if (tid < 12) {
            int u = tid - 4;
            float acc = ba[u];
            const float* x = xa + bt_ * 74;
            for (int q = 0; q < 74; ++q) acc = fmaf(x[q], Wa[q * 8 + u], acc);
            ra[u] = fmaxf(acc, 0.f);
        } else if (tid < 20) {
            int u = tid - 12;
            float acc = bv[u];
            const float* x = xv + bt_ * 35;
            for (int q = 0; q < 35; ++q) acc = fmaf(x[q], Wv[q * 8 + u], acc);
            rv[u] = fmaxf(acc, 0.f);
        }
        __syncthreads();
        if (tid == 0) {
            float s = 0.f; for (int u = 0; u < 4; ++u) s += rt[u] * rt[u];
            inv3[0] = 1.f / fmaxf(sqrtf(s), 1e-12f);
            s = 0.f; for (int u = 0; u < 8; ++u) s += ra[u] * ra[u];
            inv3[1] = 1.f / fmaxf(sqrtf(s), 1e-12f);
            s = 0.f; for (int u = 0; u < 8; ++u) s += rv[u] * rv[u];
            inv3[2] = 1.f / fmaxf(sqrtf(s), 1e-12f);
        }
        __syncthreads();
        float s0 = sm[bt_ * 2], s1 = sm[bt_ * 2 + 1];
        int spk = (s1 > s0) ? 1 : 0;
        int d = tid;
        int ti = d >> 6, ai = (d >> 3) & 7, vi = d & 7;
        float amp = (rt[ti] * inv3[0]) * (ra[ai] * inv3[1]) * (rv[vi] * inv3[2]);
        float ph = Pt[spk * 4 + ti] + Pa[spk * 8 + ai] + Pv[spk * 8 + vi];
        splitW(amp * cosf(ph), amp * sinf(ph), bf + 3 * US4, (long)colS * 256 + d, 1);
        return;
    }
    {                                      // norm: H0 = conj(normalized K rows) -> unit 44
        int k = blk - 769, i = tid;
        float vr = Kr[k * 256 + i], vi = Ki[k * 256 + i];
        red[i] = vr * vr + vi * vi;
        __syncthreads();
        for (int s = 128; s > 0; s >>= 1) { if (i < s) red[i] += red[i + s]; __syncthreads(); }
        float inv = 1.f / sqrtf(red[0]);
        splitW(vr * inv, -vi * inv, bf + 44 * US4, (long)k * 256 + i, 1);
    }
}

// ---------------- no-LDS split-complex MFMA GEMM ----------------
// C[m][n] = sum_k A[m][k] * B[n][k] (complex). Fragments loaded straight from
// global (16 rows x 64B per b128 frag-load, L2-resident) — no LDS, no barriers.
template<int LO, int WF>
__device__ void chain_body(const bf16_t* __restrict__ A, const bf16_t* __restrict__ B,
                           bf16_t* __restrict__ C,
                           int m0, int n0, int wm, int wn, int fr, int fg)
{
    constexpr int NP = LO ? 2 : 4;
    f32x4 rp[2][2] = {}, rn[2][2] = {}, im[2][2] = {};
    const bf16_t* Ab = A + (long)(m0 + wm * 32 + fr) * 256 + fg * 8;
    const bf16_t* Bb = B + (long)(n0 + wn * 32 + fr) * 256 + fg * 8;
#pragma unroll 2
    for (int ks = 0; ks < 8; ++ks) {
        bf16x8 aF[2][NP], bF[2][NP];
#pragma unroll
        for (int fm = 0; fm < 2; ++fm)
#pragma unroll
            for (int pl = 0; pl < NP; ++pl)
                aF[fm][pl] = *(const bf16x8*)(Ab + pl * 65536L + fm * 16 * 256L + ks * 32);
#pragma unroll
        for (int fn = 0; fn < 2; ++fn)
#pragma unroll
            for (int pl = 0; pl < NP; ++pl)
                bF[fn][pl] = *(const bf16x8*)(Bb + pl * 65536L + fn * 16 * 256L + ks * 32);
#pragma unroll
        for (int fm = 0; fm < 2; ++fm)
#pragma unroll
            for (int fn = 0; fn < 2; ++fn) {
                f32x4 p_ = rp[fm][fn], n_ = rn[fm][fn], i_ = im[fm][fn];
                p_ = MF(aF[fm][0], bF[fn][0], p_);
                n_ = MF(aF[fm][1], bF[fn][1], n_);
                i_ = MF(aF[fm][0], bF[fn][1], i_);
                i_ = MF(aF[fm][1], bF[fn][0], i_);
                if (!LO) {
                    p_ = MF(aF[fm][0], bF[fn][2], p_);
                    p_ = MF(aF[fm][2], bF[fn][0], p_);
                    n_ = MF(aF[fm][1], bF[fn][3], n_);
                    n_ = MF(aF[fm][3], bF[fn][1], n_);
                    i_ = MF(aF[fm][0], bF[fn][3], i_);
                    i_ = MF(aF[fm][2], bF[fn][1], i_);
                    i_ = MF(aF[fm][1], bF[fn][2], i_);
                    i_ = MF(aF[fm][3], bF[fn][0], i_);
                }
                rp[fm][fn] = p_; rn[fm][fn] = n_; im[fm][fn] = i_;
            }
    }
#pragma unroll
    for (int fm = 0; fm < 2; ++fm)
#pragma unroll
        for (int fn = 0; fn < 2; ++fn)
#pragma unroll
            for (int r4 = 0; r4 < 4; ++r4) {
                int m = m0 + wm * 32 + fm * 16 + fg * 4 + r4;
                int n = n0 + wn * 32 + fn * 16 + fr;
                float vr = rp[fm][fn][r4] - rn[fm][fn][r4];
                splitW(vr, im[fm][fn][r4], C, (long)m * 256 + n, WF);
            }
}

struct Jobs {
    long aB[4], aS[4], bB[4], cB[4], cS[4];
    int cnt[4], lo[4], wf[4];
};

__global__ __launch_bounds__(256) void k_chain(void* wsv, Jobs J)
{
    bf16_t* bf = (bf16_t*)((char*)wsv + BF_BASE_B);
    int z = blockIdx.y, j = 0;
    while (z >= J.cnt[j]) { z -= J.cnt[j]; ++j; }
    const bf16_t* A = bf + J.aB[j] + (long)z * J.aS[j];
    const bf16_t* B = bf + J.bB[j];
    bf16_t*       C = bf + J.cB[j] + (long)z * J.cS[j];
    const int m0 = (blockIdx.x & 3) * 64, n0 = (blockIdx.x >> 2) * 64;
    const int tid = threadIdx.x, lane = tid & 63, w = tid >> 6;
    const int wm = w >> 1, wn = w & 1, fr = lane & 15, fg = lane >> 4;
    if (J.lo[j])      chain_body<1, 0>(A, B, C, m0, n0, wm, wn, fr, fg);
    else if (J.wf[j]) chain_body<0, 1>(A, B, C, m0, n0, wm, wn, fr, fg);
    else              chain_body<0, 0>(A, B, C, m0, n0, wm, wn, fr, fg);
}

// ---------------- measurement v6: no-LDS fragments, flat job list ----------------
struct MJ { int pref[33]; };

__global__ __launch_bounds__(256) void k_measure6(void* wsv, MJ J)
{
    float* WF = (float*)wsv;
    bf16_t* bf = (bf16_t*)((char*)wsv + BF_BASE_B);
    // decode flat job -> (t, clo, colc, kblk)
    int bid = blockIdx.x;
    int t = 0;
    while (bid >= J.pref[t + 1]) ++t;
    int jid = bid - J.pref[t];
    const int kblk = jid & 3;
    int g = jid >> 2;
    int i = 0;
    for (;;) { int cnt2 = ((t - 4 * i) >> 3) + 1; if (g < cnt2) break; g -= cnt2; ++i; }
    const int clo = 4 * i, colc = g;
    const int chi = (clo + 4 < t + 1) ? clo + 4 : t + 1;
    const int k0 = kblk * 64;

    const int tid = threadIdx.x, lane = tid & 63, w = tid >> 6;
    const int wm = w >> 1, wn = w & 1;
    const int fr = lane & 15, fg = lane >> 4;
    __shared__ float part[64][9];
    float sacc[2][2][4] = {};

    // per-lane B-column info (per fn): col g2 = wn*32 + fn*16 + fr
    int t0_[2], bb_[2];
#pragma unroll
    for (int fn = 0; fn < 2; ++fn) {
        int g2 = wn * 32 + fn * 16 + fr;
        t0_[fn] = colc * 8 + (g2 >> 3);
        bb_[fn] = g2 & 7;
    }

    for (int c = clo; c < chi; ++c) {
        const bf16_t* Ab = bf + (44L + c) * US4 + (long)(k0 + wm * 32 + fr) * 256 + fg * 8;
        f32x4 rp[2][2] = {}, rn[2][2] = {}, im[2][2] = {};
        const bf16_t* Bb_[2];
        int val_[2];
#pragma unroll
        for (int fn = 0; fn < 2; ++fn) {
            int av = t - c - t0_[fn];
            val_[fn] = (av >= 0);
            Bb_[fn] = bf + XIB_E + (long)(val_[fn] ? av : 0) * XU
                    + (long)(t0_[fn] * 8 + bb_[fn]) * 256 + fg * 8;
        }
#pragma unroll 2
        for (int ks = 0; ks < 8; ++ks) {
            bf16x8 aF[2][2], bF[2][2];
#pragma unroll
            for (int fm = 0; fm < 2; ++fm)
#pragma unroll
                for (int pl = 0; pl < 2; ++pl)
                    aF[fm][pl] = *(const bf16x8*)(Ab + pl * 65536L + fm * 16 * 256L + ks * 32);
#pragma unroll
            for (int fn = 0; fn < 2; ++fn)
#pragma unroll
                for (int pl = 0; pl < 2; ++pl) {
                    bf16x8 v = bf16x8{};
                    if (val_[fn]) v = *(const bf16x8*)(Bb_[fn] + pl * 65536L + ks * 32);
                    bF[fn][pl] = v;
                }
#pragma unroll
            for (int fm = 0; fm < 2; ++fm)
#pragma unroll
                for (int fn = 0; fn < 2; ++fn) {
                    f32x4 p_ = rp[fm][fn], n_ = rn[fm][fn], i_ = im[fm][fn];
                    p_ = MF(aF[fm][0], bF[fn][0], p_);
                    n_ = MF(aF[fm][1], bF[fn][1], n_);
                    i_ = MF(aF[fm][0], bF[fn][1], i_);
                    i_ = MF(aF[fm][1], bF[fn][0], i_);
                    rp[fm][fn] = p_; rn[fm][fn] = n_; im[fm][fn] = i_;
                }
        }
#pragma unroll
        for (int fm = 0; fm < 2; ++fm)
#pragma unroll
            for (int fn = 0; fn < 2; ++fn)
#pragma unroll
                for (int r4 = 0; r4 < 4; ++r4) {
                    float vr = rp[fm][fn][r4] - rn[fm][fn][r4];
                    float vi = im[fm][fn][r4];
                    sacc[fm][fn][r4] += vr * vr + vi * vi;
                }
    }
    // fold weights + reduce over t0 within block, then one atomic per (k,b)
    for (int e = tid; e < 64 * 9; e += 256) (&part[0][0])[e] = 0.f;
    __syncthreads();
#pragma unroll
    for (int fm = 0; fm < 2; ++fm)
#pragma unroll
        for (int fn = 0; fn < 2; ++fn)
#pragma unroll
            for (int r4 = 0; r4 < 4; ++r4) {
                int kl = wm * 32 + fm * 16 + fg * 4 + r4;
                if (t0_[fn] <= t)
                    atomicAdd(&part[kl][bb_[fn]], WF[64 + t - t0_[fn]] * sacc[fm][fn][r4]);
            }
    __syncthreads();
    float* pacc = WF + PACC_F;
    for (int e = tid; e < 512; e += 256) {
        int kl = e >> 3, b = e & 7;
        float v = part[kl][b];
        if (v != 0.f) atomicAdd(&pacc[((t * 8 + b) << 8) + k0 + kl], v);
    }
}

// ---------------- MLP + log_softmax ----------------
__global__ __launch_bounds__(64) void k_mlp(
    const float* __restrict__ W1, const float* __restrict__ b1,
    const float* __restrict__ W2, const float* __restrict__ b2,
    const float* __restrict__ WF, float* __restrict__ out)
{
    const int t = blockIdx.x >> 3, b = blockIdx.x & 7;
    const int tid = threadIdx.x;
    __shared__ float pp[256], hh[64], oo[6];
    float ft = WF[8 + t], s2 = WF[1];
    const float* pacc = WF + PACC_F + ((t * 8 + b) << 8);
    for (int k = tid; k < 256; k += 64) pp[k] = ft + s2 * pacc[k];
    __syncthreads();
    float acc = b1[tid];
    for (int k = 0; k < 256; ++k) acc = fmaf(pp[k], W1[k * 64 + tid], acc);
    hh[tid] = fmaxf(acc, 0.f);
    __syncthreads();
    if (tid < 6) {
        float a = b2[tid];
        for (int k = 0; k < 64; ++k) a = fmaf(hh[k], W2[k * 6 + tid], a);
        oo[tid] = tanhf(a);
    }
    __syncthreads();
    if (tid == 0) {
        float m = oo[0];
        for (int c2 = 1; c2 < 6; ++c2) m = fmaxf(m, oo[c2]);
        float s = 0.f;
        for (int c2 = 0; c2 < 6; ++c2) s += expf(oo[c2] - m);
        float lse = m + logf(s);
        for (int c2 = 0; c2 < 6; ++c2) out[((long)b * 32 + t) * 6 + c2] = oo[c2] - lse;
    }
}

// ---------------- host ----------------
static inline void setJob(Jobs& J, int i, long aB, long aS, long bB, long cB, long cS,
                          int cnt, int lo, int wf)
{
    J.aB[i] = aB; J.aS[i] = aS; J.bB[i] = bB; J.cB[i] = cB; J.cS[i] = cS;
    J.cnt[i] = cnt; J.lo[i] = lo; J.wf[i] = wf;
}

extern "C" void kernel_launch(void* const* d_in, const int* in_sizes, int n_in,
                              void* d_out, int out_size, void* d_ws, size_t ws_size,
                              hipStream_t stream)
{
    const float* xt  = (const float*)d_in[0];
    const float* xa  = (const float*)d_in[1];
    const float* xv  = (const float*)d_in[2];
    const float* sm  = (const float*)d_in[3];
    const float* Wt  = (const float*)d_in[4];
    const float* bt  = (const float*)d_in[5];
    const float* Wa  = (const float*)d_in[6];
    const float* ba  = (const float*)d_in[7];
    const float* Wv  = (const float*)d_in[8];
    const float* bv  = (const float*)d_in[9];
    const float* Pt  = (const float*)d_in[10];
    const float* Pa  = (const float*)d_in[11];
    const float* Pv  = (const float*)d_in[12];
    const float* Uxr = (const float*)d_in[13];
    const float* Uxi = (const float*)d_in[14];
    const float* Uhr = (const float*)d_in[15];
    const float* Uhi = (const float*)d_in[16];
    const float* Lam = (const float*)d_in[17];
    const float* Kr  = (const float*)d_in[18];
    const float* Ki  = (const float*)d_in[19];
    const float* W1  = (const float*)d_in[20];
    const float* b1  = (const float*)d_in[21];
    const float* W2  = (const float*)d_in[22];
    const float* b2  = (const float*)d_in[23];
    float* WF  = (float*)d_ws;
    float* out = (float*)d_out;

    hipMemsetAsync(WF + PACC_F, 0, 65536 * sizeof(float), stream);
    k_prep<<<1025, 256, 0, stream>>>(xt, xa, xv, sm, Wt, bt, Wa, ba, Wv, bv,
                                     Pt, Pa, Pv, Uxr, Uxi, Uhr, Uhi, Lam, Kr, Ki, d_ws);

    auto U = [](int u) { return (long)u * US4; };
    dim3 blk(256);
    Jobs J;

    // S1: P1, PT1, Phi0 = Ux*Psi, H1 = H0*UhT
    setJob(J, 0, U(1), 0, U(2), U(4), 0, 1, 0, 1);
    setJob(J, 1, U(2), 0, U(1), U(5), 0, 1, 0, 1);
    setJob(J, 2, U(3), 0, U(0), U(12), 0, 1, 0, 1);
    setJob(J, 3, U(44), 0, U(2), U(45), 0, 1, 0, 1);
    k_chain<<<dim3(16, 4), blk, 0, stream>>>(d_ws, J);
    // S2: P2, PT2, Phi1 (B=Uh), H{2,3} (B=PT1)
    setJob(J, 0, U(4), 0, U(5), U(6), 0, 1, 0, 1);
    setJob(J, 1, U(5), 0, U(4), U(7), 0, 1, 0, 1);
    setJob(J, 2, U(12), 0, U(1), U(13), 0, 1, 0, 1);
    setJob(J, 3, U(44), US4, U(5), U(46), US4, 2, 0, 1);
    k_chain<<<dim3(16, 5), blk, 0, stream>>>(d_ws, J);
    // S3: P3, PT3, Phi{2,3} (B=P1), H{4..7} (B=PT2)
    setJob(J, 0, U(6), 0, U(7), U(8), 0, 1, 0, 1);
    setJob(J, 1, U(7), 0, U(6), U(9), 0, 1, 0, 1);
    setJob(J, 2, U(12), US4, U(4), U(14), US4, 2, 0, 1);
    setJob(J, 3, U(44), US4, U(7), U(48), US4, 4, 0, 1);
    k_chain<<<dim3(16, 8), blk, 0, stream>>>(d_ws, J);
    // S4: P4, PT4, Phi{4..7} (B=P2), H{8..15} (B=PT3)
    setJob(J, 0, U(8), 0, U(9), U(10), 0, 1, 0, 1);
    setJob(J, 1, U(9), 0, U(8), U(11), 0, 1, 0, 1);
    setJob(J, 2, U(12), US4, U(6), U(16), US4, 4, 0, 1);
    setJob(J, 3, U(44), US4, U(9), U(52), US4, 8, 0, 1);
    k_chain<<<dim3(16, 14), blk, 0, stream>>>(d_ws, J);
    // S5: Phi{8..15} (B=P3, full out — reused as A), H{16..31} (B=PT4, hi-only out)
    setJob(J, 0, U(12), US4, U(8), U(20), US4, 8, 0, 1);
    setJob(J, 1, U(44), US4, U(11), U(60), US4, 16, 0, 0);
    setJob(J, 2, 0, 0, 0, 0, 0, 0, 0, 0);
    setJob(J, 3, 0, 0, 0, 0, 0, 0, 0, 0);
    k_chain<<<dim3(16, 24), blk, 0, stream>>>(d_ws, J);
    // S6: Phi{16..31} (B=P4, hi-only out) + Xi{0..15} = Ux*Phi{0..15} (lo path)
    setJob(J, 0, U(12), US4, U(10), U(28), US4, 16, 0, 0);
    setJob(J, 1, U(12), US4, U(0), XIB_E, XU, 16, 1, 0);
    setJob(J, 2, 0, 0, 0, 0, 0, 0, 0, 0);
    setJob(J, 3, 0, 0, 0, 0, 0, 0, 0, 0);
    k_chain<<<dim3(16, 32), blk, 0, stream>>>(d_ws, J);
    // S7: Xi{16..31}
    setJob(J, 0, U(28), US4, U(0), XIB_E + 16 * XU, XU, 16, 1, 0);
    setJob(J, 1, 0, 0, 0, 0, 0, 0, 0, 0);
    setJob(J, 2, 0, 0, 0, 0, 0, 0, 0, 0);
    setJob(J, 3, 0, 0, 0, 0, 0, 0, 0, 0);
    k_chain<<<dim3(16, 16), blk, 0, stream>>>(d_ws, J);

    // measurement: flat job list
    MJ mj;
    mj.pref[0] = 0;
    for (int t = 0; t < 32; ++t) {
        int G = 0;
        for (int i2 = 0; 4 * i2 <= t; ++i2) G += ((t - 4 * i2) >> 3) + 1;
        mj.pref[t + 1] = mj.pref[t] + G * 4;
    }
    k_measure6<<<dim3(mj.pref[32], 1, 1), blk, 0, stream>>>(d_ws, mj);
    k_mlp<<<256, 64, 0, stream>>>(W1, b1, W2, b2, WF, out);
}

// Round 8
// 386.917 us; speedup vs baseline: 2.1779x; 1.0965x over previous
//
#include <hip/hip_runtime.h>

#define TT 32
#define BETA_ 0.8f

typedef __bf16 bf16_t;
typedef bf16_t bf16x8 __attribute__((ext_vector_type(8)));
typedef float f32x4 __attribute__((ext_vector_type(4)));

// ---------------- workspace layout ----------------
// f32 region: [0..256) coefs, [256..65792) PACC
#define PACC_F 256
#define BF_BASE_B 263168L             // byte offset of bf16 region (16B aligned)
// bf16 region = array of 4-plane units (planes: 0 rH, 1 iH, 2 rL, 3 iL), 262144 elems.
// Units: 0 Ux, 1 Uh, 2 UhT, 3 Psi, 4..11 {P1,PT1,P2,PT2,P3,PT3,P4,PT4},
//        12..43 Phi[a], 44..75 H[c].  Then Xi: 32 x 2-plane units (131072) at XIB_E.
#define US4 262144L
#define XU  131072L
#define XIB_E (76L * US4)

__device__ inline f32x4 MF(bf16x8 a, bf16x8 b, f32x4 c) {
    return __builtin_amdgcn_mfma_f32_16x16x32_bf16(a, b, c, 0, 0, 0);
}

__device__ inline void splitW(float vr, float vi, bf16_t* o, long idx, int full) {
    bf16_t rh = (bf16_t)vr; o[idx] = rh;
    bf16_t ih = (bf16_t)vi; o[65536L + idx] = ih;
    if (full) {
        o[2 * 65536L + idx] = (bf16_t)(vr - (float)rh);
        o[3 * 65536L + idx] = (bf16_t)(vi - (float)ih);
    }
}

// ---------------- fused prep: coef + split U + psi + norm + zero PACC ----------------
__global__ __launch_bounds__(256) void k_prep(
    const float* __restrict__ xt, const float* __restrict__ xa, const float* __restrict__ xv,
    const float* __restrict__ sm,
    const float* __restrict__ Wt, const float* __restrict__ bt,
    const float* __restrict__ Wa, const float* __restrict__ ba,
    const float* __restrict__ Wv, const float* __restrict__ bv,
    const float* __restrict__ Pt, const float* __restrict__ Pa, const float* __restrict__ Pv,
    const float* __restrict__ Uxr, const float* __restrict__ Uxi,
    const float* __restrict__ Uhr, const float* __restrict__ Uhi,
    const float* __restrict__ Lam, const float* __restrict__ Kr, const float* __restrict__ Ki,
    void* wsv)
{
    float* WF = (float*)wsv;
    bf16_t* bf = (bf16_t*)((char*)wsv + BF_BASE_B);
    const int blk = blockIdx.x, tid = threadIdx.x;
    __shared__ float red[256];
    __shared__ float rt[4], ra[8], rv[8], inv3[3];

    if (blk == 0) {
        if (tid != 0) return;
        float lam = 1.f / (1.f + expf(-Lam[0]));
        float oml = 1.f - lam;
        WF[0] = lam;
        WF[1] = BETA_ * BETA_ * lam * lam;
        float w = 1.f;
        for (int n = 0; n < 64; ++n) { WF[64 + n] = w; w *= oml; }
        float a1 = 1.f / 256.f, a2 = 1.f / 256.f;
        for (int t = 0; t < 32; ++t) {
            a1 = oml * a1;
            float y1 = BETA_ * a1 + (1.f - BETA_) / 256.f;
            a2 = lam * y1 + oml * a2;
            WF[8 + t] = BETA_ * a2 + (1.f - BETA_) / 256.f;
        }
        return;
    }
    if (blk < 513) {                       // split Ux (1..256) / Uh+UhT (257..512)
        int i = (blk - 1) & 255, j = tid;
        if (blk < 257) {
            splitW(Uxr[i * 256 + j], Uxi[i * 256 + j], bf + 0 * US4, (long)i * 256 + j, 1);
        } else {
            float vr = Uhr[i * 256 + j], vi = Uhi[i * 256 + j];
            splitW(vr, vi, bf + 1 * US4, (long)i * 256 + j, 1);
            splitW(vr, vi, bf + 2 * US4, (long)j * 256 + i, 1);
        }
        return;
    }
    if (blk < 769) {                       // psi, colS = t0*8+b
        const int colS = blk - 513;
        const int t0 = colS >> 3, b = colS & 7;
        const long bt_ = (long)b * TT + t0;
        if (tid < 4) {
            float acc = bt[tid];
            const float* x = xt + bt_ * 300;
            for (int q = 0; q < 300; ++q) acc = fmaf(x[q], Wt[q * 4 + tid], acc);
            rt[tid] = fmaxf(acc, 0.f);
        } else if (tid < 12) {
            int u = tid - 4;
            float acc = ba[u];
            const float* x = xa + bt_ * 74;
            for (int q = 0; q < 74; ++q) acc = fmaf(x[q], Wa[q * 8 + u], acc);
            ra[u] = fmaxf(acc, 0.f);
        } else if (tid < 20) {
            int u = tid - 12;
            float acc = bv[u];
            const float* x = xv + bt_ * 35;
            for (int q = 0; q < 35; ++q) acc = fmaf(x[q], Wv[q * 8 + u], acc);
            rv[u] = fmaxf(acc, 0.f);
        }
        __syncthreads();
        if (tid == 0) {
            float s = 0.f; for (int u = 0; u < 4; ++u) s += rt[u] * rt[u];
            inv3[0] = 1.f / fmaxf(sqrtf(s), 1e-12f);
            s = 0.f; for (int u = 0; u < 8; ++u) s += ra[u] * ra[u];
            inv3[1] = 1.f / fmaxf(sqrtf(s), 1e-12f);
            s = 0.f; for (int u = 0; u < 8; ++u) s += rv[u] * rv[u];
            inv3[2] = 1.f / fmaxf(sqrtf(s), 1e-12f);
        }
        __syncthreads();
        float s0 = sm[bt_ * 2], s1 = sm[bt_ * 2 + 1];
        int spk = (s1 > s0) ? 1 : 0;
        int d = tid;
        int ti = d >> 6, ai = (d >> 3) & 7, vi = d & 7;
        float amp = (rt[ti] * inv3[0]) * (ra[ai] * inv3[1]) * (rv[vi] * inv3[2]);
        float ph = Pt[spk * 4 + ti] + Pa[spk * 8 + ai] + Pv[spk * 8 + vi];
        splitW(amp * cosf(ph), amp * sinf(ph), bf + 3 * US4, (long)colS * 256 + d, 1);
        return;
    }
    if (blk < 1025) {                      // norm: H0 = conj(normalized K rows) -> unit 44
        int k = blk - 769, i = tid;
        float vr = Kr[k * 256 + i], vi = Ki[k * 256 + i];
        red[i] = vr * vr + vi * vi;
        __syncthreads();
        for (int s = 128; s > 0; s >>= 1) { if (i < s) red[i] += red[i + s]; __syncthreads(); }
        float inv = 1.f / sqrtf(red[0]);
        splitW(vr * inv, -vi * inv, bf + 44 * US4, (long)k * 256 + i, 1);
        return;
    }
    // zero PACC: blocks 1025..1280
    WF[PACC_F + (blk - 1025) * 256 + tid] = 0.f;
}

// ---------------- no-LDS split-complex MFMA GEMM, explicit ping-pong pipeline ----------
template<int LO, int WFull>
__device__ __forceinline__ void chain_body(const bf16_t* __restrict__ A,
                                           const bf16_t* __restrict__ B,
                                           bf16_t* __restrict__ C,
                                           int m0, int n0, int wm, int wn, int fr, int fg)
{
    constexpr int NP = LO ? 2 : 4;
    const bf16_t* Ab = A + (long)(m0 + wm * 32 + fr) * 256 + fg * 8;
    const bf16_t* Bb = B + (long)(n0 + wn * 32 + fr) * 256 + fg * 8;
    f32x4 rp[2][2] = {}, rn[2][2] = {}, im[2][2] = {};
    bf16x8 a0[2][NP], b0[2][NP], a1[2][NP], b1[2][NP];

#define CLD(abuf, bbuf, ks)                                                            \
    {                                                                                  \
        _Pragma("unroll") for (int fm = 0; fm < 2; ++fm)                               \
            _Pragma("unroll") for (int pl = 0; pl < NP; ++pl)                          \
                abuf[fm][pl] = *(const bf16x8*)(Ab + pl * 65536L + fm * 4096L + (ks) * 32); \
        _Pragma("unroll") for (int fn = 0; fn < 2; ++fn)                               \
            _Pragma("unroll") for (int pl = 0; pl < NP; ++pl)                          \
                bbuf[fn][pl] = *(const bf16x8*)(Bb + pl * 65536L + fn * 4096L + (ks) * 32); \
    }
#define CMM(abuf, bbuf)                                                                \
    {                                                                                  \
        _Pragma("unroll") for (int fm = 0; fm < 2; ++fm)                               \
            _Pragma("unroll") for (int fn = 0; fn < 2; ++fn) {                         \
                rp[fm][fn] = MF(abuf[fm][0], bbuf[fn][0], rp[fm][fn]);                 \
                rn[fm][fn] = MF(abuf[fm][1], bbuf[fn][1], rn[fm][fn]);                 \
                im[fm][fn] = MF(abuf[fm][0], bbuf[fn][1], im[fm][fn]);                 \
                im[fm][fn] = MF(abuf[fm][1], bbuf[fn][0], im[fm][fn]);                 \
                if (!LO) {                                                             \
                    rp[fm][fn] = MF(abuf[fm][0], bbuf[fn][2], rp[fm][fn]);             \
                    rp[fm][fn] = MF(abuf[fm][2], bbuf[fn][0], rp[fm][fn]);             \
                    rn[fm][fn] = MF(abuf[fm][1], bbuf[fn][3], rn[fm][fn]);             \
                    rn[fm][fn] = MF(abuf[fm][3], bbuf[fn][1], rn[fm][fn]);             \
                    im[fm][fn] = MF(abuf[fm][0], bbuf[fn][3], im[fm][fn]);             \
                    im[fm][fn] = MF(abuf[fm][2], bbuf[fn][1], im[fm][fn]);             \
                    im[fm][fn] = MF(abuf[fm][1], bbuf[fn][2], im[fm][fn]);             \
                    im[fm][fn] = MF(abuf[fm][3], bbuf[fn][0], im[fm][fn]);             \
                }                                                                      \
            }                                                                          \
    }
    CLD(a0, b0, 0);
    CLD(a1, b1, 1);
    CMM(a0, b0); CLD(a0, b0, 2);
    CMM(a1, b1); CLD(a1, b1, 3);
    CMM(a0, b0); CLD(a0, b0, 4);
    CMM(a1, b1); CLD(a1, b1, 5);
    CMM(a0, b0); CLD(a0, b0, 6);
    CMM(a1, b1); CLD(a1, b1, 7);
    CMM(a0, b0);
    CMM(a1, b1);
#undef CLD
#undef CMM
#pragma unroll
    for (int fm = 0; fm < 2; ++fm)
#pragma unroll
        for (int fn = 0; fn < 2; ++fn)
#pragma unroll
            for (int r4 = 0; r4 < 4; ++r4) {
                int m = m0 + wm * 32 + fm * 16 + fg * 4 + r4;
                int n = n0 + wn * 32 + fn * 16 + fr;
                float vr = rp[fm][fn][r4] - rn[fm][fn][r4];
                splitW(vr, im[fm][fn][r4], C, (long)m * 256 + n, WFull);
            }
}

struct Jobs {
    long aB[4], aS[4], bB[4], cB[4], cS[4];
    int cnt[4], lo[4], wf[4];
};

__global__ __launch_bounds__(256, 2) void k_chain(void* wsv, Jobs J)
{
    bf16_t* bf = (bf16_t*)((char*)wsv + BF_BASE_B);
    int z = blockIdx.y, j = 0;
    while (z >= J.cnt[j]) { z -= J.cnt[j]; ++j; }
    const bf16_t* A = bf + J.aB[j] + (long)z * J.aS[j];
    const bf16_t* B = bf + J.bB[j];
    bf16_t*       C = bf + J.cB[j] + (long)z * J.cS[j];
    const int m0 = (blockIdx.x & 3) * 64, n0 = (blockIdx.x >> 2) * 64;
    const int tid = threadIdx.x, lane = tid & 63, w = tid >> 6;
    const int wm = w >> 1, wn = w & 1, fr = lane & 15, fg = lane >> 4;
    if (J.lo[j])      chain_body<1, 0>(A, B, C, m0, n0, wm, wn, fr, fg);
    else if (J.wf[j]) chain_body<0, 1>(A, B, C, m0, n0, wm, wn, fr, fg);
    else              chain_body<0, 0>(A, B, C, m0, n0, wm, wn, fr, fg);
}

// ---------------- measurement v7: uniform one-c blocks, ping-pong pipeline ----------
struct MJ { int pref[33]; };

__global__ __launch_bounds__(256, 3) void k_measure7(void* wsv, MJ J)
{
    float* WF = (float*)wsv;
    bf16_t* bf = (bf16_t*)((char*)wsv + BF_BASE_B);
    // decode flat job -> (t, c, colc, kblk)
    int bid = blockIdx.x;
    int t = 0;
    while (bid >= J.pref[t + 1]) ++t;
    int jid = bid - J.pref[t];
    const int kblk = jid & 3;
    int g = jid >> 2;
    int c = 0;
    for (;;) { int cnt2 = ((t - c) >> 3) + 1; if (g < cnt2) break; g -= cnt2; ++c; }
    const int colc = g;
    const int k0 = kblk * 64;

    const int tid = threadIdx.x, lane = tid & 63, w = tid >> 6;
    const int wm = w >> 1, wn = w & 1;
    const int fr = lane & 15, fg = lane >> 4;
    __shared__ float part[64][9];

    // per-lane B-column info per fn: global col g2 = colc*64 + wn*32 + fn*16 + fr
    int g2_[2], t0_[2], val_[2];
    const bf16_t* Bb_[2];
#pragma unroll
    for (int fn = 0; fn < 2; ++fn) {
        g2_[fn] = colc * 64 + wn * 32 + fn * 16 + fr;
        t0_[fn] = g2_[fn] >> 3;
        int av = t - c - t0_[fn];
        val_[fn] = (av >= 0);
        Bb_[fn] = bf + XIB_E + (long)(val_[fn] ? av : 0) * XU + (long)g2_[fn] * 256 + fg * 8;
    }
    const bf16_t* Ab = bf + (44L + c) * US4 + (long)(k0 + wm * 32 + fr) * 256 + fg * 8;

    f32x4 rp[2][2] = {}, rn[2][2] = {}, im[2][2] = {};
    bf16x8 a0[2][2], b0[2][2], a1[2][2], b1[2][2];

#define MLD(abuf, bbuf, ks)                                                            \
    {                                                                                  \
        _Pragma("unroll") for (int fm = 0; fm < 2; ++fm)                               \
            _Pragma("unroll") for (int pl = 0; pl < 2; ++pl)                           \
                abuf[fm][pl] = *(const bf16x8*)(Ab + pl * 65536L + fm * 4096L + (ks) * 32); \
        _Pragma("unroll") for (int fn = 0; fn < 2; ++fn)                               \
            _Pragma("unroll") for (int pl = 0; pl < 2; ++pl) {                         \
                bf16x8 v = bf16x8{};                                                   \
                if (val_[fn]) v = *(const bf16x8*)(Bb_[fn] + pl * 65536L + (ks) * 32); \
                bbuf[fn][pl] = v;                                                      \
            }                                                                          \
    }
#define MMM(abuf, bbuf)                                                                \
    {                                                                                  \
        _Pragma("unroll") for (int fm = 0; fm < 2; ++fm)                               \
            _Pragma("unroll") for (int fn = 0; fn < 2; ++fn) {                         \
                rp[fm][fn] = MF(abuf[fm][0], bbuf[fn][0], rp[fm][fn]);                 \
                rn[fm][fn] = MF(abuf[fm][1], bbuf[fn][1], rn[fm][fn]);                 \
                im[fm][fn] = MF(abuf[fm][0], bbuf[fn][1], im[fm][fn]);                 \
                im[fm][fn] = MF(abuf[fm][1], bbuf[fn][0], im[fm][fn]);                 \
            }                                                                          \
    }
    MLD(a0, b0, 0);
    MLD(a1, b1, 1);
    MMM(a0, b0); MLD(a0, b0, 2);
    MMM(a1, b1); MLD(a1, b1, 3);
    MMM(a0, b0); MLD(a0, b0, 4);
    MMM(a1, b1); MLD(a1, b1, 5);
    MMM(a0, b0); MLD(a0, b0, 6);
    MMM(a1, b1); MLD(a1, b1, 7);
    MMM(a0, b0);
    MMM(a1, b1);
#undef MLD
#undef MMM

    // weight |Y|^2 and reduce in LDS, then one atomic per (k,b)
    for (int e = tid; e < 64 * 9; e += 256) (&part[0][0])[e] = 0.f;
    __syncthreads();
#pragma unroll
    for (int fm = 0; fm < 2; ++fm)
#pragma unroll
        for (int fn = 0; fn < 2; ++fn)
#pragma unroll
            for (int r4 = 0; r4 < 4; ++r4) {
                float vr = rp[fm][fn][r4] - rn[fm][fn][r4];
                float vi = im[fm][fn][r4];
                float v = vr * vr + vi * vi;
                int kl = wm * 32 + fm * 16 + fg * 4 + r4;
                if (val_[fn] && t0_[fn] <= t)
                    atomicAdd(&part[kl][g2_[fn] & 7], WF[64 + t - t0_[fn]] * v);
            }
    __syncthreads();
    float* pacc = WF + PACC_F;
    for (int e = tid; e < 512; e += 256) {
        int kl = e >> 3, b = e & 7;
        float v = part[kl][b];
        if (v != 0.f) atomicAdd(&pacc[((t * 8 + b) << 8) + k0 + kl], v);
    }
}

// ---------------- MLP + log_softmax ----------------
__global__ __launch_bounds__(64) void k_mlp(
    const float* __restrict__ W1, const float* __restrict__ b1,
    const float* __restrict__ W2, const float* __restrict__ b2,
    const float* __restrict__ WF, float* __restrict__ out)
{
    const int t = blockIdx.x >> 3, b = blockIdx.x & 7;
    const int tid = threadIdx.x;
    __shared__ float pp[256], hh[64], oo[6];
    float ft = WF[8 + t], s2 = WF[1];
    const float* pacc = WF + PACC_F + ((t * 8 + b) << 8);
    for (int k = tid; k < 256; k += 64) pp[k] = ft + s2 * pacc[k];
    __syncthreads();
    float acc = b1[tid];
    for (int k = 0; k < 256; ++k) acc = fmaf(pp[k], W1[k * 64 + tid], acc);
    hh[tid] = fmaxf(acc, 0.f);
    __syncthreads();
    if (tid < 6) {
        float a = b2[tid];
        for (int k = 0; k < 64; ++k) a = fmaf(hh[k], W2[k * 6 + tid], a);
        oo[tid] = tanhf(a);
    }
    __syncthreads();
    if (tid == 0) {
        float m = oo[0];
        for (int c2 = 1; c2 < 6; ++c2) m = fmaxf(m, oo[c2]);
        float s = 0.f;
        for (int c2 = 0; c2 < 6; ++c2) s += expf(oo[c2] - m);
        float lse = m + logf(s);
        for (int c2 = 0; c2 < 6; ++c2) out[((long)b * 32 + t) * 6 + c2] = oo[c2] - lse;
    }
}

// ---------------- host ----------------
static inline void setJob(Jobs& J, int i, long aB, long aS, long bB, long cB, long cS,
                          int cnt, int lo, int wf)
{
    J.aB[i] = aB; J.aS[i] = aS; J.bB[i] = bB; J.cB[i] = cB; J.cS[i] = cS;
    J.cnt[i] = cnt; J.lo[i] = lo; J.wf[i] = wf;
}

extern "C" void kernel_launch(void* const* d_in, const int* in_sizes, int n_in,
                              void* d_out, int out_size, void* d_ws, size_t ws_size,
                              hipStream_t stream)
{
    const float* xt  = (const float*)d_in[0];
    const float* xa  = (const float*)d_in[1];
    const float* xv  = (const float*)d_in[2];
    const float* sm  = (const float*)d_in[3];
    const float* Wt  = (const float*)d_in[4];
    const float* bt  = (const float*)d_in[5];
    const float* Wa  = (const float*)d_in[6];
    const float* ba  = (const float*)d_in[7];
    const float* Wv  = (const float*)d_in[8];
    const float* bv  = (const float*)d_in[9];
    const float* Pt  = (const float*)d_in[10];
    const float* Pa  = (const float*)d_in[11];
    const float* Pv  = (const float*)d_in[12];
    const float* Uxr = (const float*)d_in[13];
    const float* Uxi = (const float*)d_in[14];
    const float* Uhr = (const float*)d_in[15];
    const float* Uhi = (const float*)d_in[16];
    const float* Lam = (const float*)d_in[17];
    const float* Kr  = (const float*)d_in[18];
    const float* Ki  = (const float*)d_in[19];
    const float* W1  = (const float*)d_in[20];
    const float* b1  = (const float*)d_in[21];
    const float* W2  = (const float*)d_in[22];
    const float* b2  = (const float*)d_in[23];
    float* WF  = (float*)d_ws;
    float* out = (float*)d_out;

    k_prep<<<1281, 256, 0, stream>>>(xt, xa, xv, sm, Wt, bt, Wa, ba, Wv, bv,
                                     Pt, Pa, Pv, Uxr, Uxi, Uhr, Uhi, Lam, Kr, Ki, d_ws);

    auto U = [](int u) { return (long)u * US4; };
    dim3 blk(256);
    Jobs J;

    // S1: P1, PT1, Phi0 = Ux*Psi, H1 = H0*UhT
    setJob(J, 0, U(1), 0, U(2), U(4), 0, 1, 0, 1);
    setJob(J, 1, U(2), 0, U(1), U(5), 0, 1, 0, 1);
    setJob(J, 2, U(3), 0, U(0), U(12), 0, 1, 0, 1);
    setJob(J, 3, U(44), 0, U(2), U(45), 0, 1, 0, 1);
    k_chain<<<dim3(16, 4), blk, 0, stream>>>(d_ws, J);
    // S2: P2, PT2, Phi1 (B=Uh), H{2,3} (B=PT1)
    setJob(J, 0, U(4), 0, U(5), U(6), 0, 1, 0, 1);
    setJob(J, 1, U(5), 0, U(4), U(7), 0, 1, 0, 1);
    setJob(J, 2, U(12), 0, U(1), U(13), 0, 1, 0, 1);
    setJob(J, 3, U(44), US4, U(5), U(46), US4, 2, 0, 1);
    k_chain<<<dim3(16, 5), blk, 0, stream>>>(d_ws, J);
    // S3: P3, PT3, Phi{2,3} (B=P1), H{4..7} (B=PT2)
    setJob(J, 0, U(6), 0, U(7), U(8), 0, 1, 0, 1);
    setJob(J, 1, U(7), 0, U(6), U(9), 0, 1, 0, 1);
    setJob(J, 2, U(12), US4, U(4), U(14), US4, 2, 0, 1);
    setJob(J, 3, U(44), US4, U(7), U(48), US4, 4, 0, 1);
    k_chain<<<dim3(16, 8), blk, 0, stream>>>(d_ws, J);
    // S4: P4, PT4, Phi{4..7} (B=P2), H{8..15} (B=PT3)
    setJob(J, 0, U(8), 0, U(9), U(10), 0, 1, 0, 1);
    setJob(J, 1, U(9), 0, U(8), U(11), 0, 1, 0, 1);
    setJob(J, 2, U(12), US4, U(6), U(16), US4, 4, 0, 1);
    setJob(J, 3, U(44), US4, U(9), U(52), US4, 8, 0, 1);
    k_chain<<<dim3(16, 14), blk, 0, stream>>>(d_ws, J);
    // S5: Phi{8..15} (B=P3, full out), H{16..31} (B=PT4, hi-only out)
    setJob(J, 0, U(12), US4, U(8), U(20), US4, 8, 0, 1);
    setJob(J, 1, U(44), US4, U(11), U(60), US4, 16, 0, 0);
    setJob(J, 2, 0, 0, 0, 0, 0, 0, 0, 0);
    setJob(J, 3, 0, 0, 0, 0, 0, 0, 0, 0);
    k_chain<<<dim3(16, 24), blk, 0, stream>>>(d_ws, J);
    // S6: Phi{16..31} (B=P4, hi-only out) + Xi{0..15} = Ux*Phi{0..15} (lo path)
    setJob(J, 0, U(12), US4, U(10), U(28), US4, 16, 0, 0);
    setJob(J, 1, U(12), US4, U(0), XIB_E, XU, 16, 1, 0);
    setJob(J, 2, 0, 0, 0, 0, 0, 0, 0, 0);
    setJob(J, 3, 0, 0, 0, 0, 0, 0, 0, 0);
    k_chain<<<dim3(16, 32), blk, 0, stream>>>(d_ws, J);
    // S7: Xi{16..31}
    setJob(J, 0, U(28), US4, U(0), XIB_E + 16 * XU, XU, 16, 1, 0);
    setJob(J, 1, 0, 0, 0, 0, 0, 0, 0, 0);
    setJob(J, 2, 0, 0, 0, 0, 0, 0, 0, 0);
    setJob(J, 3, 0, 0, 0, 0, 0, 0, 0, 0);
    k_chain<<<dim3(16, 16), blk, 0, stream>>>(d_ws, J);

    // measurement: flat uniform job list (one c per block)
    MJ mj;
    mj.pref[0] = 0;
    for (int t = 0; t < 32; ++t) {
        int G = 0;
        for (int c = 0; c <= t; ++c) G += ((t - c) >> 3) + 1;
        mj.pref[t + 1] = mj.pref[t] + G * 4;
    }
    k_measure7<<<dim3(mj.pref[32], 1, 1), blk, 0, stream>>>(d_ws, mj);
    k_mlp<<<256, 64, 0, stream>>>(W1, b1, W2, b2, WF, out);
}